// Round 8
// baseline (1817.432 us; speedup 1.0000x reference)
//
#include <hip/hip_runtime.h>
#include <hip/hip_bf16.h>
#include <math.h>

constexpr int BATCH = 32768;
constexpr int NI   = 32;    // N_INT
constexpr int NG   = 16;    // interactions per LDS group (2 groups)
constexpr int OWND = 3;
constexpr int INTD = 7;
constexpr int AD   = 128;   // ATTN_D
constexpr int HIDN = 256;   // HID
constexpr int OUTD = 2;
constexpr int OBSD = OWND + NI * INTD;  // 227

__device__ __forceinline__ float lrelu(float x) { return x > 0.0f ? x : 0.2f * x; }
// tanh via fast exp: ~1e-6 abs error (budget 9.77e-3)
__device__ __forceinline__ float fast_tanh(float x) {
    float e = __expf(2.0f * x);
    return 1.0f - 2.0f / (e + 1.0f);
}

// One WAVE (64 lanes) per batch row; lane l owns attn dims (2l,2l+1) and
// hidden dims (4l..4l+3). Single-wave workgroup => LDS wave-private => no
// barriers. s_ie holds 16 interactions at a time (2 passes over Wk) to cut
// LDS to ~12.7 KB -> 12 blocks/CU (vs 7 in R7).
__global__ __launch_bounds__(64, 3) void fused_attn_sac(
    const float* __restrict__ obs,
    const float* __restrict__ own_W, const float* __restrict__ own_b,
    const float* __restrict__ int_W, const float* __restrict__ int_b,
    const float* __restrict__ Wq,    const float* __restrict__ Wk,
    const float* __restrict__ Wv,    const float* __restrict__ v_att,
    const float* __restrict__ proj_W,const float* __restrict__ proj_b,
    const float* __restrict__ h1_W,  const float* __restrict__ h1_b,
    const float* __restrict__ h2_W,  const float* __restrict__ h2_b,
    const float* __restrict__ out_W, const float* __restrict__ out_b,
    float* __restrict__ res)
{
    const int b  = blockIdx.x;
    const int l  = threadIdx.x;       // lane 0..63
    const int d0 = 2 * l;             // owned attn dims
    const int h0 = 4 * l;             // owned hidden dims

    __shared__ __align__(16) float s_obs[OBSD + 1];   // 912 B
    __shared__ __align__(16) float s_ie[NG][AD];      // 8 KB (one group)
    __shared__ __align__(16) float s_own[AD];
    __shared__ __align__(16) float s_sv[AD];
    __shared__ __align__(16) float s_ctx[AD];
    __shared__ __align__(16) float s_x[HIDN];
    __shared__ __align__(16) float s_h[HIDN];

    // ---- stage obs row ----
    const float* orow = obs + (size_t)b * OBSD;
    for (int i = l; i < OBSD; i += 64) s_obs[i] = orow[i];

    // ---- own_e ----
    float2 ob = *(const float2*)(own_b + d0);
    float oe0 = ob.x, oe1 = ob.y;
    #pragma unroll
    for (int j = 0; j < OWND; j++) {
        float2 w = *(const float2*)(own_W + j * AD + d0);
        float x = s_obs[j];
        oe0 += x * w.x; oe1 += x * w.y;
    }
    oe0 = lrelu(oe0); oe1 = lrelu(oe1);
    *(float2*)(s_own + d0) = make_float2(oe0, oe1);

    // ---- q ----
    float q0 = 0.f, q1 = 0.f;
    #pragma unroll 2
    for (int c = 0; c < AD; c += 4) {
        float4 f = *(const float4*)(s_own + c);
        float2 a0 = *(const float2*)(Wq + (c + 0) * AD + d0);
        float2 a1 = *(const float2*)(Wq + (c + 1) * AD + d0);
        float2 a2 = *(const float2*)(Wq + (c + 2) * AD + d0);
        float2 a3 = *(const float2*)(Wq + (c + 3) * AD + d0);
        q0 += f.x * a0.x + f.y * a1.x + f.z * a2.x + f.w * a3.x;
        q1 += f.x * a0.y + f.y * a1.y + f.z * a2.y + f.w * a3.y;
    }

    // ---- int_e + k-projection in 2 groups of 16 ----
    float wi0[INTD], wi1[INTD];
    #pragma unroll
    for (int j = 0; j < INTD; j++) {
        float2 w = *(const float2*)(int_W + j * AD + d0);
        wi0[j] = w.x; wi1[j] = w.y;
    }
    float2 ibv = *(const float2*)(int_b + d0);
    unsigned pmask = 0u;
    float kx[NI], ky[NI];
    #pragma unroll
    for (int n = 0; n < NI; n++) { kx[n] = 0.f; ky[n] = 0.f; }

    #pragma unroll
    for (int g = 0; g < 2; g++) {
        const int base = g * NG;
        // group int_e -> s_ie (lane writes its 2 dims for 16 n)
        #pragma unroll
        for (int n = 0; n < NG; n++) {
            float z0 = ibv.x, z1 = ibv.y, su = 0.f;
            #pragma unroll
            for (int j = 0; j < INTD; j++) {
                float x = s_obs[OWND + (base + n) * INTD + j];
                su += fabsf(x);
                z0 += x * wi0[j]; z1 += x * wi1[j];
            }
            if (su < 1e-6f) pmask |= (1u << (base + n));
            *(float2*)(&s_ie[n][d0]) = make_float2(lrelu(z0), lrelu(z1));
        }
        // one pass over Wk for this group: 8 FMAs per ds_read_b128
        #pragma unroll 2
        for (int c = 0; c < AD; c += 4) {
            float2 a0 = *(const float2*)(Wk + (c + 0) * AD + d0);
            float2 a1 = *(const float2*)(Wk + (c + 1) * AD + d0);
            float2 a2 = *(const float2*)(Wk + (c + 2) * AD + d0);
            float2 a3 = *(const float2*)(Wk + (c + 3) * AD + d0);
            #pragma unroll
            for (int n = 0; n < NG; n++) {
                float4 f = *(const float4*)(&s_ie[n][c]);
                kx[base + n] += f.x * a0.x + f.y * a1.x + f.z * a2.x + f.w * a3.x;
                ky[base + n] += f.x * a0.y + f.y * a1.y + f.z * a2.y + f.w * a3.y;
            }
        }
    }

    // ---- scores (butterfly leaves sum in all lanes) ----
    float2 vav = *(const float2*)(v_att + d0);
    float sc[NI];
    #pragma unroll
    for (int n = 0; n < NI; n++) {
        float p = vav.x * fast_tanh(q0 + kx[n]) + vav.y * fast_tanh(q1 + ky[n]);
        #pragma unroll
        for (int off = 32; off >= 1; off >>= 1) p += __shfl_xor(p, off, 64);
        sc[n] = p;
    }

    // ---- masked softmax + nan_to_num (lane-redundant, in registers) ----
    float m = -INFINITY;
    #pragma unroll
    for (int n = 0; n < NI; n++) if (!((pmask >> n) & 1)) m = fmaxf(m, sc[n]);
    const bool anyv = (pmask != 0xFFFFFFFFu);
    float den = 0.f;
    #pragma unroll
    for (int n = 0; n < NI; n++) {
        float e = (((pmask >> n) & 1) || !anyv) ? 0.f : __expf(sc[n] - m);
        sc[n] = e; den += e;
    }
    float rden = anyv ? 1.0f / den : 0.0f;

    // ---- sv = alpha @ int_e (recompute int_e per-lane; s_ie group 0 was
    //      overwritten). Same expression/operands as above -> same values. ----
    float sv0 = 0.f, sv1 = 0.f;
    #pragma unroll
    for (int n = 0; n < NI; n++) {
        float z0 = ibv.x, z1 = ibv.y;
        #pragma unroll
        for (int j = 0; j < INTD; j++) {
            float x = s_obs[OWND + n * INTD + j];
            z0 += x * wi0[j]; z1 += x * wi1[j];
        }
        float a = sc[n] * rden;
        sv0 += a * lrelu(z0); sv1 += a * lrelu(z1);
    }
    *(float2*)(s_sv + d0) = make_float2(sv0, sv1);

    // ---- ctx = sv @ Wv ----
    float c0 = 0.f, c1 = 0.f;
    #pragma unroll 2
    for (int c = 0; c < AD; c += 4) {
        float4 f = *(const float4*)(s_sv + c);
        float2 a0 = *(const float2*)(Wv + (c + 0) * AD + d0);
        float2 a1 = *(const float2*)(Wv + (c + 1) * AD + d0);
        float2 a2 = *(const float2*)(Wv + (c + 2) * AD + d0);
        float2 a3 = *(const float2*)(Wv + (c + 3) * AD + d0);
        c0 += f.x * a0.x + f.y * a1.x + f.z * a2.x + f.w * a3.x;
        c1 += f.x * a0.y + f.y * a1.y + f.z * a2.y + f.w * a3.y;
    }
    *(float2*)(s_ctx + d0) = make_float2(c0, c1);

    // ---- attn_vec = tanh(ctx @ proj_W + proj_b) ----
    float2 pb = *(const float2*)(proj_b + d0);
    float av0 = pb.x, av1 = pb.y;
    #pragma unroll 2
    for (int c = 0; c < AD; c += 4) {
        float4 f = *(const float4*)(s_ctx + c);
        float2 a0 = *(const float2*)(proj_W + (c + 0) * AD + d0);
        float2 a1 = *(const float2*)(proj_W + (c + 1) * AD + d0);
        float2 a2 = *(const float2*)(proj_W + (c + 2) * AD + d0);
        float2 a3 = *(const float2*)(proj_W + (c + 3) * AD + d0);
        av0 += f.x * a0.x + f.y * a1.x + f.z * a2.x + f.w * a3.x;
        av1 += f.x * a0.y + f.y * a1.y + f.z * a2.y + f.w * a3.y;
    }
    av0 = fast_tanh(av0); av1 = fast_tanh(av1);
    *(float2*)(s_x + d0)      = make_float2(oe0, oe1);
    *(float2*)(s_x + AD + d0) = make_float2(av0, av1);

    // ---- h1: lane owns hidden dims h0..h0+3 -> float4 weight loads ----
    float4 hb = *(const float4*)(h1_b + h0);
    float hA = hb.x, hB = hb.y, hC = hb.z, hD = hb.w;
    #pragma unroll 2
    for (int c = 0; c < HIDN; c += 4) {
        float4 f = *(const float4*)(s_x + c);
        float4 w0 = *(const float4*)(h1_W + (c + 0) * HIDN + h0);
        float4 w1 = *(const float4*)(h1_W + (c + 1) * HIDN + h0);
        float4 w2 = *(const float4*)(h1_W + (c + 2) * HIDN + h0);
        float4 w3 = *(const float4*)(h1_W + (c + 3) * HIDN + h0);
        hA += f.x * w0.x + f.y * w1.x + f.z * w2.x + f.w * w3.x;
        hB += f.x * w0.y + f.y * w1.y + f.z * w2.y + f.w * w3.y;
        hC += f.x * w0.z + f.y * w1.z + f.z * w2.z + f.w * w3.z;
        hD += f.x * w0.w + f.y * w1.w + f.z * w2.w + f.w * w3.w;
    }
    *(float4*)(s_h + h0) = make_float4(lrelu(hA), lrelu(hB), lrelu(hC), lrelu(hD));

    // ---- h2 (results kept in registers) ----
    float4 eb = *(const float4*)(h2_b + h0);
    float rA = eb.x, rB = eb.y, rC = eb.z, rD = eb.w;
    #pragma unroll 2
    for (int c = 0; c < HIDN; c += 4) {
        float4 f = *(const float4*)(s_h + c);
        float4 w0 = *(const float4*)(h2_W + (c + 0) * HIDN + h0);
        float4 w1 = *(const float4*)(h2_W + (c + 1) * HIDN + h0);
        float4 w2 = *(const float4*)(h2_W + (c + 2) * HIDN + h0);
        float4 w3 = *(const float4*)(h2_W + (c + 3) * HIDN + h0);
        rA += f.x * w0.x + f.y * w1.x + f.z * w2.x + f.w * w3.x;
        rB += f.x * w0.y + f.y * w1.y + f.z * w2.y + f.w * w3.y;
        rC += f.x * w0.z + f.y * w1.z + f.z * w2.z + f.w * w3.z;
        rD += f.x * w0.w + f.y * w1.w + f.z * w2.w + f.w * w3.w;
    }
    rA = lrelu(rA); rB = lrelu(rB); rC = lrelu(rC); rD = lrelu(rD);

    // ---- out = h2 @ out_W + out_b (lane rows h0..h0+3) ----
    float4 wo0 = *(const float4*)(out_W + (size_t)h0 * OUTD);        // rows h0, h0+1
    float4 wo1 = *(const float4*)(out_W + (size_t)(h0 + 2) * OUTD);  // rows h0+2, h0+3
    float o0 = rA * wo0.x + rB * wo0.z + rC * wo1.x + rD * wo1.z;
    float o1 = rA * wo0.y + rB * wo0.w + rC * wo1.y + rD * wo1.w;
    #pragma unroll
    for (int off = 32; off >= 1; off >>= 1) {
        o0 += __shfl_xor(o0, off, 64);
        o1 += __shfl_xor(o1, off, 64);
    }
    if (l == 0) {
        *(float2*)(res + (size_t)b * OUTD) = make_float2(o0 + out_b[0], o1 + out_b[1]);
    }
}

// Final copy: d_out's last writer is this trivial kernel at the end of the
// stream (fixes the post-timing d_out clobber seen in R5 — do not remove).
__global__ __launch_bounds__(256) void copy_out(const float* __restrict__ src,
                                               float* __restrict__ dst, int n4) {
    int i = blockIdx.x * 256 + threadIdx.x;
    if (i < n4) ((float4*)dst)[i] = ((const float4*)src)[i];
}

extern "C" void kernel_launch(void* const* d_in, const int* in_sizes, int n_in,
                              void* d_out, int out_size, void* d_ws, size_t ws_size,
                              hipStream_t stream) {
    const float* obs    = (const float*)d_in[0];
    const float* own_W  = (const float*)d_in[1];
    const float* own_b  = (const float*)d_in[2];
    const float* int_W  = (const float*)d_in[3];
    const float* int_b  = (const float*)d_in[4];
    const float* Wq     = (const float*)d_in[5];
    const float* Wk     = (const float*)d_in[6];
    const float* Wv     = (const float*)d_in[7];
    const float* v_att  = (const float*)d_in[8];
    const float* proj_W = (const float*)d_in[9];
    const float* proj_b = (const float*)d_in[10];
    const float* h1_W   = (const float*)d_in[11];
    const float* h1_b   = (const float*)d_in[12];
    const float* h2_W   = (const float*)d_in[13];
    const float* h2_b   = (const float*)d_in[14];
    const float* out_W  = (const float*)d_in[15];
    const float* out_b  = (const float*)d_in[16];

    const size_t res_bytes = (size_t)BATCH * OUTD * sizeof(float);  // 256 KB
    const bool use_ws = (ws_size >= res_bytes);   // call-invariant
    float* res = use_ws ? (float*)d_ws : (float*)d_out;

    fused_attn_sac<<<BATCH, 64, 0, stream>>>(
        obs, own_W, own_b, int_W, int_b, Wq, Wk, Wv, v_att,
        proj_W, proj_b, h1_W, h1_b, h2_W, h2_b, out_W, out_b, res);

    if (use_ws) {
        const int n4 = BATCH * OUTD / 4;
        copy_out<<<(n4 + 255) / 256, 256, 0, stream>>>(res, (float*)d_out, n4);
    }
}